// Round 7
// baseline (174.713 us; speedup 1.0000x reference)
//
#include <hip/hip_runtime.h>

#define N_NODES 16384
#define N_EDGES 524288

typedef short bf16x8 __attribute__((ext_vector_type(8)));
typedef float f32x4 __attribute__((ext_vector_type(4)));

__device__ __forceinline__ ushort f2bf(float a) {
    uint u = __float_as_uint(a);
    return (ushort)((u + 0x7fff + ((u >> 16) & 1)) >> 16);
}
__device__ __forceinline__ uint pack2bf(float a, float b) {
    return (uint)f2bf(a) | ((uint)f2bf(b) << 16);
}
__device__ __forceinline__ float bflo(uint v) { return __uint_as_float(v << 16); }
__device__ __forceinline__ float bfhi(uint v) { return __uint_as_float(v & 0xffff0000u); }

// ---------------- zero count (replaces graph-captured memset node) ----------
__global__ void zero_count_kernel(uint4* __restrict__ count4) {
    count4[blockIdx.x * 256 + threadIdx.x] = make_uint4(0, 0, 0, 0);   // 4096 uint4 = 64KB
}

// ---------------- histogram of dst ------------------------------------------
__global__ void hist_kernel(const int* __restrict__ dst, int* __restrict__ count) {
    int e = blockIdx.x * 256 + threadIdx.x;
    if (e < N_EDGES) atomicAdd(&count[dst[e]], 1);
}

// -------- exclusive scan -> indptr (+ cursor copy), plus dinv ---------------
__global__ void scan_kernel(const int* __restrict__ count, int* __restrict__ indptr,
                            int* __restrict__ cursor, float* __restrict__ dinv) {
    __shared__ int part[256];
    int t = threadIdx.x;
    int base = t * 64;
    int local[64];
    int s = 0;
#pragma unroll
    for (int i = 0; i < 64; ++i) { local[i] = s; s += count[base + i]; }
    part[t] = s;
    __syncthreads();
    for (int off = 1; off < 256; off <<= 1) {
        int v = (t >= off) ? part[t - off] : 0;
        __syncthreads();
        part[t] += v;
        __syncthreads();
    }
    int prefix = (t == 0) ? 0 : part[t - 1];
#pragma unroll
    for (int i = 0; i < 64; ++i) {
        int p = prefix + local[i];
        indptr[base + i] = p;
        cursor[base + i] = p;
        dinv[base + i] = rsqrtf((float)(count[base + i] + 1));
    }
    if (t == 255) indptr[N_NODES] = part[255];
}

// ---------------- counting-sort scatter (cursor holds absolute pos) ---------
__global__ void scatter_kernel(const int* __restrict__ src, const int* __restrict__ dst,
                               int* __restrict__ cursor, int* __restrict__ sorted_src) {
    int e = blockIdx.x * 256 + threadIdx.x;
    if (e < N_EDGES) {
        int d = dst[e];
        int p = atomicAdd(&cursor[d], 1);
        sorted_src[p] = src[e];
    }
}

// ---------------- x -> bf16 -------------------------------------------------
__global__ void cvt_x_kernel(const float* __restrict__ x, ushort* __restrict__ x_bf) {
    int i = (blockIdx.x * 256 + threadIdx.x) * 4;
    float4 v = *(const float4*)(x + i);
    ushort4 o;
    o.x = f2bf(v.x); o.y = f2bf(v.y); o.z = f2bf(v.z); o.w = f2bf(v.w);
    *(ushort4*)(x_bf + i) = o;
}

// ---------------- pack W^T bf16: wT[n][k], n<128 emb, else asn ---------------
__global__ void cvt_w_kernel(const float* __restrict__ W_emb, const float* __restrict__ W_asn,
                             ushort* __restrict__ wT) {
    int idx = blockIdx.x * 256 + threadIdx.x;   // 32768
    int k = idx >> 8, n = idx & 255;
    float v = n < 128 ? W_emb[k * 128 + n] : W_asn[k * 128 + (n - 128)];
    wT[(size_t)n * 128 + k] = f2bf(v);
}

// ------ h[N,256](bf16) = (x_bf @ wT^T) * dinv[row] via MFMA ------------------
__global__ __launch_bounds__(512) void gemm_xw_mfma(
        const ushort* __restrict__ x_bf, const ushort* __restrict__ wT,
        const float* __restrict__ dinv, ushort* __restrict__ h) {
    int l = threadIdx.x & 63, w = threadIdx.x >> 6;
    int m0 = blockIdx.x * 64 + (w >> 2) * 32;
    int n0 = (w & 3) * 64;
    int lr = l & 15, lk = (l >> 4) * 8;
    f32x4 acc[2][4] = {};
#pragma unroll
    for (int kk = 0; kk < 128; kk += 32) {
        bf16x8 a[2], b[4];
#pragma unroll
        for (int fm = 0; fm < 2; ++fm)
            a[fm] = *(const bf16x8*)(x_bf + (size_t)(m0 + fm * 16 + lr) * 128 + kk + lk);
#pragma unroll
        for (int fn = 0; fn < 4; ++fn)
            b[fn] = *(const bf16x8*)(wT + (size_t)(n0 + fn * 16 + lr) * 128 + kk + lk);
#pragma unroll
        for (int fm = 0; fm < 2; ++fm)
#pragma unroll
            for (int fn = 0; fn < 4; ++fn)
                acc[fm][fn] = __builtin_amdgcn_mfma_f32_16x16x32_bf16(
                    a[fm], b[fn], acc[fm][fn], 0, 0, 0);
    }
    int rbase = (l >> 4) * 4;
#pragma unroll
    for (int fm = 0; fm < 2; ++fm)
#pragma unroll
        for (int r = 0; r < 4; ++r) {
            int row = m0 + fm * 16 + rbase + r;
            float dv = dinv[row];
#pragma unroll
            for (int fn = 0; fn < 4; ++fn)
                h[(size_t)row * 256 + n0 + fn * 16 + lr] = f2bf(acc[fm][fn][r] * dv);
        }
}

// ---------------- GCN aggregation + bias + relu / softmax -------------------
__global__ void conv_kernel(const ushort* __restrict__ h, const int* __restrict__ indptr,
                            const int* __restrict__ sorted_src, const float* __restrict__ dinv,
                            const float* __restrict__ b_emb, const float* __restrict__ b_asn,
                            float* __restrict__ S_out, uint* __restrict__ S_bf,
                            uint* __restrict__ xe_bf) {
    const uint* __restrict__ hp = (const uint*)h;
    int wv = threadIdx.x >> 6, lane = threadIdx.x & 63;
    int task = blockIdx.x * 4 + wv;
    int d = task >> 1, role = task & 1;
    int beg = indptr[d], end = indptr[d + 1];
    float di = dinv[d];
    int off = role * 64 + lane;
    float ax = 0.f, ay = 0.f;
    for (int ch = beg; ch < end; ch += 64) {
        int take = end - ch; if (take > 64) take = 64;
        int myi = sorted_src[ch + (lane < take ? lane : 0)];
        int i = 0;
        for (; i + 4 <= take; i += 4) {
            int s0 = __shfl(myi, i),     s1 = __shfl(myi, i + 1);
            int s2 = __shfl(myi, i + 2), s3 = __shfl(myi, i + 3);
            uint v0 = hp[(size_t)s0 * 128 + off];
            uint v1 = hp[(size_t)s1 * 128 + off];
            uint v2 = hp[(size_t)s2 * 128 + off];
            uint v3 = hp[(size_t)s3 * 128 + off];
            ax += (bflo(v0) + bflo(v1)) + (bflo(v2) + bflo(v3));
            ay += (bfhi(v0) + bfhi(v1)) + (bfhi(v2) + bfhi(v3));
        }
        for (; i < take; ++i) {
            int s = __shfl(myi, i);
            uint v = hp[(size_t)s * 128 + off];
            ax += bflo(v); ay += bfhi(v);
        }
    }
    uint vd = hp[(size_t)d * 128 + off];
    ax += bflo(vd); ay += bfhi(vd);
    ax *= di; ay *= di;
    const float2* __restrict__ bp = (const float2*)(role ? b_asn : b_emb);
    float2 bb = bp[lane];
    ax += bb.x; ay += bb.y;
    if (role == 0) {
        float ox = fmaxf(ax, 0.f), oy = fmaxf(ay, 0.f);
        xe_bf[(size_t)d * 64 + lane] = pack2bf(ox, oy);
    } else {
        float m = fmaxf(ax, ay);
#pragma unroll
        for (int o2 = 32; o2; o2 >>= 1) m = fmaxf(m, __shfl_xor(m, o2));
        float e0 = __expf(ax - m), e1 = __expf(ay - m);
        float s = e0 + e1;
#pragma unroll
        for (int o2 = 32; o2; o2 >>= 1) s += __shfl_xor(s, o2);
        float inv = 1.f / s;
        float p0 = e0 * inv, p1 = e1 * inv;
        ((float2*)S_out)[(size_t)d * 64 + lane] = make_float2(p0, p1);
        S_bf[(size_t)d * 64 + lane] = pack2bf(p0, p1);
    }
}

// -------- Mt[d][:] = sum over UNIQUE srcs s of d of S[s,:]  (packed bf16) ---
__global__ void mt_kernel(const uint* __restrict__ S_bf, const int* __restrict__ indptr,
                          const int* __restrict__ sorted_src, uint* __restrict__ Mt_bf) {
    __shared__ int ss[4][1024];
    int wv = threadIdx.x >> 6, lane = threadIdx.x & 63;
    int d = blockIdx.x * 4 + wv;
    int beg = indptr[d];
    int len = indptr[d + 1] - beg;
    if (len > 1024) len = 1024;
    for (int i = lane; i < len; i += 64) ss[wv][i] = sorted_src[beg + i];
    __syncthreads();
    for (int i = lane; i < len; i += 64) {
        int s = ss[wv][i];
        for (int j = 0; j < i; ++j)
            if (ss[wv][j] == s) { ss[wv][i] = -1; break; }
    }
    __syncthreads();
    float ax = 0.f, ay = 0.f;
    for (int ch = 0; ch < len; ch += 64) {
        int take = len - ch; if (take > 64) take = 64;
        int myv = ss[wv][ch + (lane < take ? lane : 0)];
        int i = 0;
        for (; i + 4 <= take; i += 4) {
            int s0 = __shfl(myv, i),     s1 = __shfl(myv, i + 1);
            int s2 = __shfl(myv, i + 2), s3 = __shfl(myv, i + 3);
            float m0 = s0 >= 0 ? 1.f : 0.f, m1 = s1 >= 0 ? 1.f : 0.f;
            float m2 = s2 >= 0 ? 1.f : 0.f, m3 = s3 >= 0 ? 1.f : 0.f;
            uint v0 = S_bf[(size_t)(s0 >= 0 ? s0 : 0) * 64 + lane];
            uint v1 = S_bf[(size_t)(s1 >= 0 ? s1 : 0) * 64 + lane];
            uint v2 = S_bf[(size_t)(s2 >= 0 ? s2 : 0) * 64 + lane];
            uint v3 = S_bf[(size_t)(s3 >= 0 ? s3 : 0) * 64 + lane];
            ax += (bflo(v0) * m0 + bflo(v1) * m1) + (bflo(v2) * m2 + bflo(v3) * m3);
            ay += (bfhi(v0) * m0 + bfhi(v1) * m1) + (bfhi(v2) * m2 + bfhi(v3) * m3);
        }
        for (; i < take; ++i) {
            int s = __shfl(myv, i);
            if (s >= 0) {
                uint v = S_bf[(size_t)s * 64 + lane];
                ax += bflo(v); ay += bfhi(v);
            }
        }
    }
    Mt_bf[(size_t)d * 64 + lane] = pack2bf(ax, ay);
}

// ------ LDS-tiled transpose: [16384][128] bf16 -> [128][16384] bf16 ---------
__global__ __launch_bounds__(256) void transpose_kernel(
        const ushort* __restrict__ S_bf, const ushort* __restrict__ xe_bf,
        const ushort* __restrict__ Mt_bf, ushort* __restrict__ S_T,
        ushort* __restrict__ xe_T, ushort* __restrict__ Mt_T) {
    __shared__ ushort tile[128][130];
    const ushort* __restrict__ src;
    ushort* __restrict__ dst;
    if (blockIdx.y == 0)      { src = S_bf;  dst = S_T; }
    else if (blockIdx.y == 1) { src = xe_bf; dst = xe_T; }
    else                      { src = Mt_bf; dst = Mt_T; }
    int tid = threadIdx.x;
    int n0 = blockIdx.x * 128;
    for (int i = tid; i < 2048; i += 256) {
        int r = i >> 4, c8 = (i & 15) << 3;
        const uint* p = (const uint*)(src + (size_t)(n0 + r) * 128 + c8);
        uint* t = (uint*)&tile[r][c8];
        t[0] = p[0]; t[1] = p[1]; t[2] = p[2]; t[3] = p[3];
    }
    __syncthreads();
    for (int i = tid; i < 2048; i += 256) {
        int ch = i >> 4, n8 = (i & 15) << 3;
        ushort v[8];
#pragma unroll
        for (int j = 0; j < 8; ++j) v[j] = tile[n8 + j][ch];
        uint4 o;
        o.x = (uint)v[0] | ((uint)v[1] << 16);
        o.y = (uint)v[2] | ((uint)v[3] << 16);
        o.z = (uint)v[4] | ((uint)v[5] << 16);
        o.w = (uint)v[6] | ((uint)v[7] << 16);
        *(uint4*)(dst + (size_t)ch * N_NODES + n0 + n8) = o;
    }
}

// ---- stage 1 (MFMA): partial[g][c] = A^T_chunk @ B_chunk, chunk=128 k ------
__global__ __launch_bounds__(512) void pool_stage1_mfma(
        const ushort* __restrict__ S_T, const ushort* __restrict__ xe_T,
        const ushort* __restrict__ Mt_T, float* __restrict__ part) {
    const ushort* __restrict__ A = blockIdx.y ? Mt_T : S_T;
    const ushort* __restrict__ B = blockIdx.y ? S_T : xe_T;
    float* __restrict__ out = part + (size_t)blockIdx.y * (128 * N_NODES) +
                              (size_t)blockIdx.x * 16384;
    int l = threadIdx.x & 63, w = threadIdx.x >> 6;
    int m0 = (w >> 2) * 64;
    int n0 = (w & 3) * 32;
    int lr = l & 15, lk = (l >> 4) * 8;
    int kb = blockIdx.x * 128;
    f32x4 acc[4][2] = {};
#pragma unroll
    for (int kk = 0; kk < 128; kk += 32) {
        bf16x8 a[4], b[2];
#pragma unroll
        for (int fm = 0; fm < 4; ++fm)
            a[fm] = *(const bf16x8*)(A + (size_t)(m0 + fm * 16 + lr) * N_NODES + kb + kk + lk);
#pragma unroll
        for (int fn = 0; fn < 2; ++fn)
            b[fn] = *(const bf16x8*)(B + (size_t)(n0 + fn * 16 + lr) * N_NODES + kb + kk + lk);
#pragma unroll
        for (int fm = 0; fm < 4; ++fm)
#pragma unroll
            for (int fn = 0; fn < 2; ++fn)
                acc[fm][fn] = __builtin_amdgcn_mfma_f32_16x16x32_bf16(
                    a[fm], b[fn], acc[fm][fn], 0, 0, 0);
    }
    int rbase = (l >> 4) * 4;
#pragma unroll
    for (int fm = 0; fm < 4; ++fm)
#pragma unroll
        for (int r = 0; r < 4; ++r)
#pragma unroll
            for (int fn = 0; fn < 2; ++fn)
                out[(size_t)(m0 + fm * 16 + rbase + r) * 128 + n0 + fn * 16 + lr] =
                    acc[fm][fn][r];
}

// ---- stage 2: out[idx] = sum_p partial[p][idx] -----------------------------
__global__ void pool_reduce_kernel(const float* __restrict__ part, float* __restrict__ out) {
    int idx = blockIdx.x * 256 + threadIdx.x;
    int g = idx >> 14;
    int o = idx & 16383;
    const float* __restrict__ p = part + (size_t)g * (128 * N_NODES) + o;
    float s = 0.f;
#pragma unroll 8
    for (int c = 0; c < 128; ++c) s += p[(size_t)c * 16384];
    out[idx] = s;
}

extern "C" void kernel_launch(void* const* d_in, const int* in_sizes, int n_in,
                              void* d_out, int out_size, void* d_ws, size_t ws_size,
                              hipStream_t stream) {
    const float* x      = (const float*)d_in[0];
    const int*   ei     = (const int*)d_in[1];
    const float* W_emb  = (const float*)d_in[2];
    const float* b_emb  = (const float*)d_in[3];
    const float* W_asn  = (const float*)d_in[4];
    const float* b_asn  = (const float*)d_in[5];
    const int* src = ei;
    const int* dst = ei + N_EDGES;

    float* out = (float*)d_out;
    float* S_out = out + 32768;   // outputs: x_pooled(16384), A_pooled(16384), S(N*128)

    // workspace (32 MB peak, liveness-overlapped) — same map as R6
    char* ws = (char*)d_ws;
    ushort* x_bf   = (ushort*)(ws + 0);
    ushort* Mt_T   = (ushort*)(ws + 0);
    ushort* h      = (ushort*)(ws + 4194304);
    ushort* S_T    = (ushort*)(ws + 4194304);
    ushort* xe_T   = (ushort*)(ws + 8388608);
    int*    sorted = (int*)   (ws + 12582912);
    ushort* wT     = (ushort*)(ws + 14680064);
    int*    count  = (int*)   (ws + 15204352);
    int*    indptr = (int*)   (ws + 15269888);
    int*    cursor = (int*)   (ws + 15400960);
    float*  dinv   = (float*) (ws + 15466496);
    uint*   S_bf   = (uint*)  (ws + 16777216);
    uint*   xe_bf  = (uint*)  (ws + 20971520);
    uint*   Mt_bf  = (uint*)  (ws + 25165824);
    float*  part   = (float*) (ws + 16777216);

    zero_count_kernel<<<16, 256, 0, stream>>>((uint4*)count);
    hist_kernel<<<2048, 256, 0, stream>>>(dst, count);
    scan_kernel<<<1, 256, 0, stream>>>(count, indptr, cursor, dinv);
    scatter_kernel<<<2048, 256, 0, stream>>>(src, dst, cursor, sorted);
    cvt_x_kernel<<<2048, 256, 0, stream>>>(x, x_bf);
    cvt_w_kernel<<<128, 256, 0, stream>>>(W_emb, W_asn, wT);
    gemm_xw_mfma<<<256, 512, 0, stream>>>(x_bf, wT, dinv, h);
    conv_kernel<<<8192, 256, 0, stream>>>(h, indptr, sorted, dinv, b_emb, b_asn,
                                          S_out, S_bf, xe_bf);
    mt_kernel<<<4096, 256, 0, stream>>>(S_bf, indptr, sorted, Mt_bf);
    transpose_kernel<<<dim3(128, 3), 256, 0, stream>>>(
        (const ushort*)S_bf, (const ushort*)xe_bf, (const ushort*)Mt_bf, S_T, xe_T, Mt_T);
    pool_stage1_mfma<<<dim3(128, 2), 512, 0, stream>>>(S_T, xe_T, Mt_T, part);
    pool_reduce_kernel<<<128, 256, 0, stream>>>(part, out);
}

// Round 8
// 157.655 us; speedup vs baseline: 1.1082x; 1.1082x over previous
//
#include <hip/hip_runtime.h>

#define N_NODES 16384
#define N_EDGES 524288

typedef short bf16x8 __attribute__((ext_vector_type(8)));
typedef float f32x4 __attribute__((ext_vector_type(4)));

__device__ __forceinline__ ushort f2bf(float a) {
    uint u = __float_as_uint(a);
    return (ushort)((u + 0x7fff + ((u >> 16) & 1)) >> 16);
}
__device__ __forceinline__ uint pack2bf(float a, float b) {
    return (uint)f2bf(a) | ((uint)f2bf(b) << 16);
}
__device__ __forceinline__ float bflo(uint v) { return __uint_as_float(v << 16); }
__device__ __forceinline__ float bfhi(uint v) { return __uint_as_float(v & 0xffff0000u); }

// ---- prep: zero count (blocks 0..15) + pack W^T bf16 (blocks 16..143) ------
__global__ void prep_kernel(uint4* __restrict__ count4, const float* __restrict__ W_emb,
                            const float* __restrict__ W_asn, ushort* __restrict__ wT) {
    int b = blockIdx.x;
    if (b < 16) { count4[b * 256 + threadIdx.x] = make_uint4(0, 0, 0, 0); return; }
    int idx = (b - 16) * 256 + threadIdx.x;          // 0..32767
    int k = idx >> 8, n = idx & 255;
    float v = n < 128 ? W_emb[k * 128 + n] : W_asn[k * 128 + (n - 128)];
    wT[(size_t)n * 128 + k] = f2bf(v);
}

// ---------------- histogram of dst ------------------------------------------
__global__ void hist_kernel(const int* __restrict__ dst, int* __restrict__ count) {
    int e = blockIdx.x * 256 + threadIdx.x;
    if (e < N_EDGES) atomicAdd(&count[dst[e]], 1);
}

// -------- exclusive scan -> indptr (+ cursor copy), plus dinv ---------------
__global__ void scan_kernel(const int* __restrict__ count, int* __restrict__ indptr,
                            int* __restrict__ cursor, float* __restrict__ dinv) {
    __shared__ int part[256];
    int t = threadIdx.x;
    int base = t * 64;
    int local[64];
    int s = 0;
#pragma unroll
    for (int i = 0; i < 64; ++i) { local[i] = s; s += count[base + i]; }
    part[t] = s;
    __syncthreads();
    for (int off = 1; off < 256; off <<= 1) {
        int v = (t >= off) ? part[t - off] : 0;
        __syncthreads();
        part[t] += v;
        __syncthreads();
    }
    int prefix = (t == 0) ? 0 : part[t - 1];
#pragma unroll
    for (int i = 0; i < 64; ++i) {
        int p = prefix + local[i];
        indptr[base + i] = p;
        cursor[base + i] = p;
        dinv[base + i] = rsqrtf((float)(count[base + i] + 1));
    }
    if (t == 255) indptr[N_NODES] = part[255];
}

// ---- fused: counting-sort scatter (blocks <2048) + x' = x*dinv -> bf16 -----
__global__ void scatter_cvt_kernel(const int* __restrict__ src, const int* __restrict__ dst,
                                   int* __restrict__ cursor, int* __restrict__ sorted_src,
                                   const float* __restrict__ x, const float* __restrict__ dinv,
                                   ushort* __restrict__ x_bf) {
    int b = blockIdx.x;
    if (b < 2048) {
        int e = b * 256 + threadIdx.x;
        int d = dst[e];
        int p = atomicAdd(&cursor[d], 1);
        sorted_src[p] = src[e];
    } else {
        int i = (b - 2048) * 256 + threadIdx.x;      // float4 index, 524288 total
        float4 v = *(const float4*)(x + (size_t)i * 4);
        float dv = dinv[i >> 5];                     // row = (i*4)>>7, uniform per float4
        ushort4 o;
        o.x = f2bf(v.x * dv); o.y = f2bf(v.y * dv);
        o.z = f2bf(v.z * dv); o.w = f2bf(v.w * dv);
        *(ushort4*)(x_bf + (size_t)i * 4) = o;
    }
}

// ---- agg[d,:] = (sum_{s in N(d)} x'[s,:] + x'[d,:]) * dinv[d]  (bf16) ------
// one wave per node; lane owns packed channel pair (2*lane, 2*lane+1).
__global__ void agg_kernel(const uint* __restrict__ xp, const int* __restrict__ indptr,
                           const int* __restrict__ sorted_src, const float* __restrict__ dinv,
                           uint* __restrict__ agg) {
    int wv = threadIdx.x >> 6, lane = threadIdx.x & 63;
    int d = blockIdx.x * 4 + wv;
    int beg = indptr[d], end = indptr[d + 1];
    float ax = 0.f, ay = 0.f;
    for (int ch = beg; ch < end; ch += 64) {
        int take = end - ch; if (take > 64) take = 64;
        int myi = sorted_src[ch + (lane < take ? lane : 0)];
        int i = 0;
        for (; i + 4 <= take; i += 4) {
            int s0 = __shfl(myi, i),     s1 = __shfl(myi, i + 1);
            int s2 = __shfl(myi, i + 2), s3 = __shfl(myi, i + 3);
            uint v0 = xp[(size_t)s0 * 64 + lane];
            uint v1 = xp[(size_t)s1 * 64 + lane];
            uint v2 = xp[(size_t)s2 * 64 + lane];
            uint v3 = xp[(size_t)s3 * 64 + lane];
            ax += (bflo(v0) + bflo(v1)) + (bflo(v2) + bflo(v3));
            ay += (bfhi(v0) + bfhi(v1)) + (bfhi(v2) + bfhi(v3));
        }
        for (; i < take; ++i) {
            int s = __shfl(myi, i);
            uint v = xp[(size_t)s * 64 + lane];
            ax += bflo(v); ay += bfhi(v);
        }
    }
    uint vd = xp[(size_t)d * 64 + lane];             // self loop
    ax += bflo(vd); ay += bfhi(vd);
    float di = dinv[d];
    agg[(size_t)d * 64 + lane] = pack2bf(ax * di, ay * di);
}

// ---- fused GEMM + epilogue: [agg @ wT^T] + bias; relu -> xe_bf;  -----------
// row-softmax over asn half -> S_out (fp32) + S_bf (packed bf16).
// 256 blocks x 512 thr (8 waves: 2m x 4n), block tile 64 rows x 256 cols.
__global__ __launch_bounds__(512) void gemm_fused_mfma(
        const ushort* __restrict__ agg, const ushort* __restrict__ wT,
        const float* __restrict__ b_emb, const float* __restrict__ b_asn,
        float* __restrict__ S_out, uint* __restrict__ S_bf, uint* __restrict__ xe_bf) {
    __shared__ float hs[64][257];                    // +1 pad: 4-way max on r/w
    int l = threadIdx.x & 63, w = threadIdx.x >> 6;
    int lrow0 = (w >> 2) * 32;
    int m0 = blockIdx.x * 64 + lrow0;
    int n0 = (w & 3) * 64;
    int lr = l & 15, lk = (l >> 4) * 8;
    f32x4 acc[2][4] = {};
#pragma unroll
    for (int kk = 0; kk < 128; kk += 32) {
        bf16x8 a[2], b[4];
#pragma unroll
        for (int fm = 0; fm < 2; ++fm)
            a[fm] = *(const bf16x8*)(agg + (size_t)(m0 + fm * 16 + lr) * 128 + kk + lk);
#pragma unroll
        for (int fn = 0; fn < 4; ++fn)
            b[fn] = *(const bf16x8*)(wT + (size_t)(n0 + fn * 16 + lr) * 128 + kk + lk);
#pragma unroll
        for (int fm = 0; fm < 2; ++fm)
#pragma unroll
            for (int fn = 0; fn < 4; ++fn)
                acc[fm][fn] = __builtin_amdgcn_mfma_f32_16x16x32_bf16(
                    a[fm], b[fn], acc[fm][fn], 0, 0, 0);
    }
    int rbase = (l >> 4) * 4;
    const float* __restrict__ bvec = n0 < 128 ? b_emb : b_asn;
    int bcol0 = n0 & 127;
#pragma unroll
    for (int fn = 0; fn < 4; ++fn) {
        float bias = bvec[bcol0 + fn * 16 + lr];
#pragma unroll
        for (int fm = 0; fm < 2; ++fm)
#pragma unroll
            for (int r = 0; r < 4; ++r)
                hs[lrow0 + fm * 16 + rbase + r][n0 + fn * 16 + lr] = acc[fm][fn][r] + bias;
    }
    __syncthreads();
    int g = threadIdx.x >> 3, sub = threadIdx.x & 7;     // row g, 8 threads/row
    size_t grow = blockIdx.x * 64 + g;
    // emb half: relu + pack -> xe_bf
    uint w8[8];
#pragma unroll
    for (int j = 0; j < 8; ++j) {
        float a0 = fmaxf(hs[g][sub * 16 + 2 * j], 0.f);
        float a1 = fmaxf(hs[g][sub * 16 + 2 * j + 1], 0.f);
        w8[j] = pack2bf(a0, a1);
    }
    *(uint4*)(&xe_bf[grow * 64 + sub * 8])     = make_uint4(w8[0], w8[1], w8[2], w8[3]);
    *(uint4*)(&xe_bf[grow * 64 + sub * 8 + 4]) = make_uint4(w8[4], w8[5], w8[6], w8[7]);
    // asn half: softmax over 128 cols (8 threads x 16 each, shfl within wave)
    float v[16];
#pragma unroll
    for (int j = 0; j < 16; ++j) v[j] = hs[g][128 + sub * 16 + j];
    float m = v[0];
#pragma unroll
    for (int j = 1; j < 16; ++j) m = fmaxf(m, v[j]);
    m = fmaxf(m, __shfl_xor(m, 1));
    m = fmaxf(m, __shfl_xor(m, 2));
    m = fmaxf(m, __shfl_xor(m, 4));
    float s = 0.f;
#pragma unroll
    for (int j = 0; j < 16; ++j) { v[j] = __expf(v[j] - m); s += v[j]; }
    s += __shfl_xor(s, 1);
    s += __shfl_xor(s, 2);
    s += __shfl_xor(s, 4);
    float inv = 1.f / s;
#pragma unroll
    for (int j = 0; j < 16; ++j) v[j] *= inv;
#pragma unroll
    for (int q = 0; q < 4; ++q)
        *(float4*)(&S_out[grow * 128 + sub * 16 + 4 * q]) =
            make_float4(v[4 * q], v[4 * q + 1], v[4 * q + 2], v[4 * q + 3]);
#pragma unroll
    for (int j = 0; j < 8; ++j) w8[j] = pack2bf(v[2 * j], v[2 * j + 1]);
    *(uint4*)(&S_bf[grow * 64 + sub * 8])     = make_uint4(w8[0], w8[1], w8[2], w8[3]);
    *(uint4*)(&S_bf[grow * 64 + sub * 8 + 4]) = make_uint4(w8[4], w8[5], w8[6], w8[7]);
}

// -------- Mt[d][:] = sum over UNIQUE srcs s of d of S[s,:]  (packed bf16) ---
__global__ void mt_kernel(const uint* __restrict__ S_bf, const int* __restrict__ indptr,
                          const int* __restrict__ sorted_src, uint* __restrict__ Mt_bf) {
    __shared__ int ss[4][1024];
    int wv = threadIdx.x >> 6, lane = threadIdx.x & 63;
    int d = blockIdx.x * 4 + wv;
    int beg = indptr[d];
    int len = indptr[d + 1] - beg;
    if (len > 1024) len = 1024;
    for (int i = lane; i < len; i += 64) ss[wv][i] = sorted_src[beg + i];
    __syncthreads();
    for (int i = lane; i < len; i += 64) {
        int s = ss[wv][i];
        for (int j = 0; j < i; ++j)
            if (ss[wv][j] == s) { ss[wv][i] = -1; break; }
    }
    __syncthreads();
    float ax = 0.f, ay = 0.f;
    for (int ch = 0; ch < len; ch += 64) {
        int take = len - ch; if (take > 64) take = 64;
        int myv = ss[wv][ch + (lane < take ? lane : 0)];
        int i = 0;
        for (; i + 4 <= take; i += 4) {
            int s0 = __shfl(myv, i),     s1 = __shfl(myv, i + 1);
            int s2 = __shfl(myv, i + 2), s3 = __shfl(myv, i + 3);
            float m0 = s0 >= 0 ? 1.f : 0.f, m1 = s1 >= 0 ? 1.f : 0.f;
            float m2 = s2 >= 0 ? 1.f : 0.f, m3 = s3 >= 0 ? 1.f : 0.f;
            uint v0 = S_bf[(size_t)(s0 >= 0 ? s0 : 0) * 64 + lane];
            uint v1 = S_bf[(size_t)(s1 >= 0 ? s1 : 0) * 64 + lane];
            uint v2 = S_bf[(size_t)(s2 >= 0 ? s2 : 0) * 64 + lane];
            uint v3 = S_bf[(size_t)(s3 >= 0 ? s3 : 0) * 64 + lane];
            ax += (bflo(v0) * m0 + bflo(v1) * m1) + (bflo(v2) * m2 + bflo(v3) * m3);
            ay += (bfhi(v0) * m0 + bfhi(v1) * m1) + (bfhi(v2) * m2 + bfhi(v3) * m3);
        }
        for (; i < take; ++i) {
            int s = __shfl(myv, i);
            if (s >= 0) {
                uint v = S_bf[(size_t)s * 64 + lane];
                ax += bflo(v); ay += bfhi(v);
            }
        }
    }
    Mt_bf[(size_t)d * 64 + lane] = pack2bf(ax, ay);
}

// ------ LDS-tiled transpose: [16384][128] bf16 -> [128][16384] bf16 ---------
__global__ __launch_bounds__(256) void transpose_kernel(
        const ushort* __restrict__ S_bf, const ushort* __restrict__ xe_bf,
        const ushort* __restrict__ Mt_bf, ushort* __restrict__ S_T,
        ushort* __restrict__ xe_T, ushort* __restrict__ Mt_T) {
    __shared__ ushort tile[128][130];
    const ushort* __restrict__ src;
    ushort* __restrict__ dst;
    if (blockIdx.y == 0)      { src = S_bf;  dst = S_T; }
    else if (blockIdx.y == 1) { src = xe_bf; dst = xe_T; }
    else                      { src = Mt_bf; dst = Mt_T; }
    int tid = threadIdx.x;
    int n0 = blockIdx.x * 128;
    for (int i = tid; i < 2048; i += 256) {
        int r = i >> 4, c8 = (i & 15) << 3;
        const uint* p = (const uint*)(src + (size_t)(n0 + r) * 128 + c8);
        uint* t = (uint*)&tile[r][c8];
        t[0] = p[0]; t[1] = p[1]; t[2] = p[2]; t[3] = p[3];
    }
    __syncthreads();
    for (int i = tid; i < 2048; i += 256) {
        int ch = i >> 4, n8 = (i & 15) << 3;
        ushort v[8];
#pragma unroll
        for (int j = 0; j < 8; ++j) v[j] = tile[n8 + j][ch];
        uint4 o;
        o.x = (uint)v[0] | ((uint)v[1] << 16);
        o.y = (uint)v[2] | ((uint)v[3] << 16);
        o.z = (uint)v[4] | ((uint)v[5] << 16);
        o.w = (uint)v[6] | ((uint)v[7] << 16);
        *(uint4*)(dst + (size_t)ch * N_NODES + n0 + n8) = o;
    }
}

// ---- stage 1 (MFMA): partial[g][c] = A^T_chunk @ B_chunk, chunk=256 k ------
__global__ __launch_bounds__(512) void pool_stage1_mfma(
        const ushort* __restrict__ S_T, const ushort* __restrict__ xe_T,
        const ushort* __restrict__ Mt_T, float* __restrict__ part) {
    const ushort* __restrict__ A = blockIdx.y ? Mt_T : S_T;
    const ushort* __restrict__ B = blockIdx.y ? S_T : xe_T;
    float* __restrict__ out = part + (size_t)blockIdx.y * (64 * 16384) +
                              (size_t)blockIdx.x * 16384;
    int l = threadIdx.x & 63, w = threadIdx.x >> 6;
    int m0 = (w >> 2) * 64;
    int n0 = (w & 3) * 32;
    int lr = l & 15, lk = (l >> 4) * 8;
    int kb = blockIdx.x * 256;
    f32x4 acc[4][2] = {};
#pragma unroll 2
    for (int kk = 0; kk < 256; kk += 32) {
        bf16x8 a[4], b[2];
#pragma unroll
        for (int fm = 0; fm < 4; ++fm)
            a[fm] = *(const bf16x8*)(A + (size_t)(m0 + fm * 16 + lr) * N_NODES + kb + kk + lk);
#pragma unroll
        for (int fn = 0; fn < 2; ++fn)
            b[fn] = *(const bf16x8*)(B + (size_t)(n0 + fn * 16 + lr) * N_NODES + kb + kk + lk);
#pragma unroll
        for (int fm = 0; fm < 4; ++fm)
#pragma unroll
            for (int fn = 0; fn < 2; ++fn)
                acc[fm][fn] = __builtin_amdgcn_mfma_f32_16x16x32_bf16(
                    a[fm], b[fn], acc[fm][fn], 0, 0, 0);
    }
    int rbase = (l >> 4) * 4;
#pragma unroll
    for (int fm = 0; fm < 4; ++fm)
#pragma unroll
        for (int r = 0; r < 4; ++r)
#pragma unroll
            for (int fn = 0; fn < 2; ++fn)
                out[(size_t)(m0 + fm * 16 + rbase + r) * 128 + n0 + fn * 16 + lr] =
                    acc[fm][fn][r];
}

// ---- stage 2: out[idx] = sum_p partial[p][idx] -----------------------------
__global__ void pool_reduce_kernel(const float* __restrict__ part, float* __restrict__ out) {
    int idx = blockIdx.x * 256 + threadIdx.x;
    int g = idx >> 14;
    int o = idx & 16383;
    const float* __restrict__ p = part + (size_t)g * (64 * 16384) + o;
    float s = 0.f;
#pragma unroll 8
    for (int c = 0; c < 64; ++c) s += p[(size_t)c * 16384];
    out[idx] = s;
}

extern "C" void kernel_launch(void* const* d_in, const int* in_sizes, int n_in,
                              void* d_out, int out_size, void* d_ws, size_t ws_size,
                              hipStream_t stream) {
    const float* x      = (const float*)d_in[0];
    const int*   ei     = (const int*)d_in[1];
    const float* W_emb  = (const float*)d_in[2];
    const float* b_emb  = (const float*)d_in[3];
    const float* W_asn  = (const float*)d_in[4];
    const float* b_asn  = (const float*)d_in[5];
    const int* src = ei;
    const int* dst = ei + N_EDGES;

    float* out = (float*)d_out;
    float* S_out = out + 32768;   // outputs: x_pooled(16384), A_pooled(16384), S(N*128)

    // workspace (<=32 MB, liveness-overlapped):
    //  [0,4M)   x_bf (cvt->agg), then S_T (transpose->stage1)
    //  [4,8M)   agg  (agg->gemm), then xe_T (transpose->stage1)
    //  [8,12M)  Mt_T (transpose->stage1)
    //  [12,14M) sorted (scatter->mt)
    //  [14M+)   wT, count, indptr, cursor, dinv
    //  [16,20M) S_bf (gemm->mt/transpose), [20,24M) xe_bf (gemm->transpose)
    //  [16,24M) part (stage1->reduce; S_bf/xe_bf dead)
    //  [24,28M) Mt_bf (mt->transpose)
    char* ws = (char*)d_ws;
    ushort* x_bf   = (ushort*)(ws + 0);
    ushort* S_T    = (ushort*)(ws + 0);
    ushort* agg    = (ushort*)(ws + 4194304);
    ushort* xe_T   = (ushort*)(ws + 4194304);
    ushort* Mt_T   = (ushort*)(ws + 8388608);
    int*    sorted = (int*)   (ws + 12582912);
    ushort* wT     = (ushort*)(ws + 14680064);
    int*    count  = (int*)   (ws + 15204352);
    int*    indptr = (int*)   (ws + 15269888);
    int*    cursor = (int*)   (ws + 15400960);
    float*  dinv   = (float*) (ws + 15466496);
    uint*   S_bf   = (uint*)  (ws + 16777216);
    uint*   xe_bf  = (uint*)  (ws + 20971520);
    float*  part   = (float*) (ws + 16777216);
    uint*   Mt_bf  = (uint*)  (ws + 25165824);

    prep_kernel<<<144, 256, 0, stream>>>((uint4*)count, W_emb, W_asn, wT);
    hist_kernel<<<2048, 256, 0, stream>>>(dst, count);
    scan_kernel<<<1, 256, 0, stream>>>(count, indptr, cursor, dinv);
    scatter_cvt_kernel<<<4096, 256, 0, stream>>>(src, dst, cursor, sorted, x, dinv, x_bf);
    agg_kernel<<<4096, 256, 0, stream>>>((const uint*)x_bf, indptr, sorted, dinv, (uint*)agg);
    gemm_fused_mfma<<<256, 512, 0, stream>>>(agg, wT, b_emb, b_asn, S_out, S_bf, xe_bf);
    mt_kernel<<<4096, 256, 0, stream>>>(S_bf, indptr, sorted, Mt_bf);
    transpose_kernel<<<dim3(128, 3), 256, 0, stream>>>(
        (const ushort*)S_bf, (const ushort*)xe_bf, (const ushort*)Mt_bf, S_T, xe_T, Mt_T);
    pool_stage1_mfma<<<dim3(64, 2), 512, 0, stream>>>(S_T, xe_T, Mt_T, part);
    pool_reduce_kernel<<<128, 256, 0, stream>>>(part, out);
}